// Round 1
// baseline (1362.019 us; speedup 1.0000x reference)
//
#include <hip/hip_runtime.h>
#include <stdint.h>

#define B_  128
#define C_  512
#define G_  20
#define K2  4608      // C_*9, conv GEMM K
#define FCK 18432     // C_*36, fc GEMM K

typedef unsigned short u16;
typedef unsigned int   u32;
typedef __attribute__((ext_vector_type(8))) short  short8;
typedef __attribute__((ext_vector_type(4))) float  float4v;

__device__ __forceinline__ u16 f2bf(float f) {
  u32 u = __builtin_bit_cast(u32, f);
  u = (u + 0x7fffu + ((u >> 16) & 1u)) >> 16;   // RNE
  return (u16)u;
}

__device__ __forceinline__ void load_lds16(const void* g, void* l) {
  __builtin_amdgcn_global_load_lds(
      (const __attribute__((address_space(1))) void*)(uintptr_t)g,
      (__attribute__((address_space(3))) void*)(uint32_t)(uintptr_t)l,
      16, 0, 0);
}

// ---------------- landmarks -> integer crop positions ----------------
__global__ void k_pos(const float* __restrict__ y, int* __restrict__ cx, int* __restrict__ cy) {
  int b = blockIdx.x * blockDim.x + threadIdx.x;
  if (b >= B_) return;
  const int   I1[10] = {21,18,19,41,38,49,48,51,61,56};
  const int   I2[10] = {22,25,24,46,43,53,54,57,63,58};
  const float CF[10] = {-0.5f, -1.0f/3.0f, 1.0f/3.0f, 1.0f, 0.f,0.f,0.f,0.f,0.f, 0.5f};
  const float* yb = y + b * 136;
  float ruler = fabsf(yb[2*39] - yb[2*42]);
  for (int j = 0; j < 10; ++j) {
    float off = ruler * CF[j];
    float vx1 = yb[2*I1[j]];
    float vy1 = yb[2*I1[j]+1] + off;
    float vx2 = yb[2*I2[j]];
    float vy2 = yb[2*I2[j]+1] + off;
    int px1 = (int)(vx1 * 0.0625f); px1 = min(max(px1,1),12);
    int py1 = (int)(vy1 * 0.0625f); py1 = min(max(py1,1),12);
    int px2 = (int)(vx2 * 0.0625f); px2 = min(max(px2,1),12);
    int py2 = (int)(vy2 * 0.0625f); py2 = min(max(py2,1),12);
    cx[b*20 + 2*j]   = px1;  cx[b*20 + 2*j+1] = px2;
    cy[b*20 + 2*j]   = py1;  cy[b*20 + 2*j+1] = py2;
  }
}

// ------------- conv_w f32 [o][ci][t] -> bf16 Wb[o][t*512+ci] -------------
__global__ void k_convw(const float* __restrict__ w, u16* __restrict__ wb) {
  int tid = blockIdx.x * 256 + threadIdx.x;       // 10240*512 threads
  int o = tid >> 9, ci = tid & 511;
  const float* src = w + (size_t)tid * 9;         // (o*512+ci)*9
  u16* dst = wb + (size_t)o * K2 + ci;
  #pragma unroll
  for (int t = 0; t < 9; ++t) dst[t*512] = f2bf(src[t]);
}

// ------- fc_w f32 [g][i][o:150] -> bf16 Wfcb[g][o:160(pad0)][i] -------
__global__ void k_fcw(const float* __restrict__ fw, u16* __restrict__ wfcb) {
  size_t tid = (size_t)blockIdx.x * 256 + threadIdx.x;  // 20*160*2304
  int ic   = (int)(tid % 2304);
  int rest = (int)(tid / 2304);
  int o = rest % 160, g = rest / 160;
  int i0 = ic * 8;
  u16 vals[8];
  if (o < 150) {
    const float* src = fw + ((size_t)g*FCK + i0) * 150 + o;
    #pragma unroll
    for (int k = 0; k < 8; ++k) vals[k] = f2bf(src[(size_t)k*150]);
  } else {
    #pragma unroll
    for (int k = 0; k < 8; ++k) vals[k] = 0;
  }
  *(short8*)(wfcb + ((size_t)(g*160 + o))*FCK + i0) = *(short8*)vals;
}

// ------- crop + bilinear 2x upsample -> up3[g][b][pp(8x8 pad)][ci] bf16 -------
__global__ void __launch_bounds__(256) k_up3(const float* __restrict__ x,
                                             const int* __restrict__ cx,
                                             const int* __restrict__ cy,
                                             u16* __restrict__ up3) {
  __shared__ float crop[3][3][C_];   // [r][s][ci]
  int bg = blockIdx.x;               // b*20+g
  int b = bg / 20, g = bg % 20;
  int X = cx[bg] - 1, Y = cy[bg] - 1;
  const float* xb = x + (size_t)b * (C_*14*14);
  int t = threadIdx.x;
  for (int it = 0; it < 6; ++it) {
    int idx = it*256 + t;            // 1536 = 512*3
    int r = idx >> 9, ci = idx & 511;
    const float* srow = xb + ci*196 + (Y + r)*14 + X;
    crop[r][0][ci] = srow[0];
    crop[r][1][ci] = srow[1];
    crop[r][2][ci] = srow[2];
  }
  __syncthreads();
  const int   R0[6] = {0,0,0,1,1,1};
  const float WA[6] = {1.f, .75f, .25f, .75f, .25f, 0.f};
  u16* dstbase = up3 + ((size_t)g*B_ + b) * 64 * C_;
  for (int it = 0; it < 16; ++it) {
    int cidx = it*256 + t;           // 4096 chunks of 8 ci
    int pp = cidx >> 6;
    int c8 = (cidx & 63) * 8;
    int ph = pp >> 3, pw = pp & 7;
    u16 outv[8];
    if (ph == 0 || ph == 7 || pw == 0 || pw == 7) {
      #pragma unroll
      for (int j = 0; j < 8; ++j) outv[j] = 0;
    } else {
      int oh = ph - 1, ow = pw - 1;
      int r0 = R0[oh]; float wy0 = WA[oh], wy1 = 1.f - WA[oh];
      int s0 = R0[ow]; float wx0 = WA[ow], wx1 = 1.f - WA[ow];
      #pragma unroll
      for (int j = 0; j < 8; ++j) {
        int ci = c8 + j;
        float v = wy0*(wx0*crop[r0][s0][ci]   + wx1*crop[r0][s0+1][ci])
                + wy1*(wx0*crop[r0+1][s0][ci] + wx1*crop[r0+1][s0+1][ci]);
        outv[j] = f2bf(v);
      }
    }
    *(short8*)(dstbase + (size_t)pp*C_ + c8) = *(short8*)outv;
  }
}

// ---------------- grouped conv as implicit GEMM (bf16 MFMA) ----------------
// per group g: D[co][n] = sum_k Wb[g*512+co][k] * P[n][k],  k=t*512+ci, n=b*36+pix
__global__ void __launch_bounds__(256) k_conv(const u16* __restrict__ wb,
                                              const u16* __restrict__ up3,
                                              const float* __restrict__ conv_b,
                                              u16* __restrict__ feat) {
  __shared__ __align__(16) u16 As[128*64];
  __shared__ __align__(16) u16 Bs[128*64];
  int nt = blockIdx.x;   // 0..35
  int mt = blockIdx.y;   // 0..3
  int g  = blockIdx.z;   // 0..19
  int tid = threadIdx.x;
  int lane = tid & 63, w = tid >> 6;
  int wr = w >> 1, wc = w & 1;
  int rl = lane >> 3, s = lane & 7;
  int l15 = lane & 15, l4 = lane >> 4;

  const u16* gA[4]; u16* lA[4];
  #pragma unroll
  for (int i = 0; i < 4; ++i) {
    int rA = w*32 + i*8 + rl;
    int c  = s ^ (rA & 7);                         // source pre-swizzle (rule #21)
    gA[i] = wb + (size_t)(g*512 + mt*128 + rA) * K2 + c*8;
    lA[i] = (u16*)As + (w*32 + i*8) * 64;
  }
  const u16* gB[4]; u16* lB[4];
  #pragma unroll
  for (int i = 0; i < 4; ++i) {
    int rB = w*32 + i*8 + rl;
    int n  = nt*128 + rB;
    unsigned bb = (unsigned)n / 36u;
    unsigned pix = (unsigned)n % 36u;
    int pixA = (int)(pix/6u)*8 + (int)(pix%6u);
    int c = s ^ (rB & 7);
    gB[i] = up3 + (((size_t)g*B_ + bb)*64 + pixA) * C_ + c*8;
    lB[i] = (u16*)Bs + (w*32 + i*8) * 64;
  }

  float4v acc[4][4];
  #pragma unroll
  for (int mi = 0; mi < 4; ++mi)
    #pragma unroll
    for (int nj = 0; nj < 4; ++nj) acc[mi][nj] = (float4v){0.f,0.f,0.f,0.f};

  for (int step = 0; step < 72; ++step) {
    int t9  = step >> 3;
    int ci0 = (step & 7) * 64;
    size_t kofsA = (size_t)step * 64;
    size_t kofsB = (size_t)((t9/3)*8 + (t9%3)) * C_ + ci0;  // pixel delta + ci
    __syncthreads();
    #pragma unroll
    for (int i = 0; i < 4; ++i) load_lds16(gA[i] + kofsA, lA[i]);
    #pragma unroll
    for (int i = 0; i < 4; ++i) load_lds16(gB[i] + kofsB, lB[i]);
    __syncthreads();   // compiler drains vmcnt before barrier (m97 structure)

    short8 a[4][2], bf[4][2];
    #pragma unroll
    for (int kb = 0; kb < 2; ++kb) {
      #pragma unroll
      for (int mi = 0; mi < 4; ++mi) {
        int row = wr*64 + mi*16 + l15;
        int cb  = (kb*64 + l4*16) ^ ((row & 7) << 4);
        a[mi][kb] = *(const short8*)((const char*)As + row*128 + cb);
      }
      #pragma unroll
      for (int nj = 0; nj < 4; ++nj) {
        int row = wc*64 + nj*16 + l15;
        int cb  = (kb*64 + l4*16) ^ ((row & 7) << 4);
        bf[nj][kb] = *(const short8*)((const char*)Bs + row*128 + cb);
      }
    }
    #pragma unroll
    for (int kb = 0; kb < 2; ++kb)
      #pragma unroll
      for (int mi = 0; mi < 4; ++mi)
        #pragma unroll
        for (int nj = 0; nj < 4; ++nj)
          acc[mi][nj] = __builtin_amdgcn_mfma_f32_16x16x32_bf16(
              a[mi][kb], bf[nj][kb], acc[mi][nj], 0, 0, 0);
  }

  // epilogue: bias + relu -> feat[g][b][co*36+pix] (bf16)
  float bias[4][4];
  #pragma unroll
  for (int mi = 0; mi < 4; ++mi)
    #pragma unroll
    for (int r = 0; r < 4; ++r)
      bias[mi][r] = conv_b[g*512 + mt*128 + wr*64 + mi*16 + l4*4 + r];
  #pragma unroll
  for (int nj = 0; nj < 4; ++nj) {
    int n = nt*128 + wc*64 + nj*16 + l15;
    unsigned bb = (unsigned)n / 36u;
    unsigned pix = (unsigned)n % 36u;
    size_t base = ((size_t)g*B_ + bb)*FCK + pix;
    #pragma unroll
    for (int mi = 0; mi < 4; ++mi)
      #pragma unroll
      for (int r = 0; r < 4; ++r) {
        int m = mt*128 + wr*64 + mi*16 + l4*4 + r;
        float v = fmaxf(acc[mi][nj][r] + bias[mi][r], 0.f);
        feat[base + (size_t)m*36] = f2bf(v);
      }
  }
}

// ---------------- FC: per-group [128 x 18432] x [18432 x 160], split-K ----------------
__global__ void __launch_bounds__(256) k_fc(const u16* __restrict__ feat,
                                            const u16* __restrict__ wfcb,
                                            float* __restrict__ accum) {
  __shared__ __align__(16) u16 As[128*64];
  __shared__ __align__(16) u16 Bs[160*64];
  int sp = blockIdx.x;   // 0..15 k-split
  int g  = blockIdx.y;
  int tid = threadIdx.x;
  int lane = tid & 63, w = tid >> 6;
  int wr = w >> 1, wc = w & 1;
  int rl = lane >> 3, s = lane & 7;
  int l15 = lane & 15, l4 = lane >> 4;

  const u16* gA[4]; u16* lA[4];
  #pragma unroll
  for (int i = 0; i < 4; ++i) {
    int r = w*32 + i*8 + rl;
    int c = s ^ (r & 7);
    gA[i] = feat + ((size_t)g*B_ + r)*FCK + c*8;
    lA[i] = (u16*)As + (w*32 + i*8) * 64;
  }
  const u16* gB[5]; u16* lB[5];
  #pragma unroll
  for (int i = 0; i < 5; ++i) {
    int r = w*40 + i*8 + rl;
    int c = s ^ (r & 7);
    gB[i] = wfcb + ((size_t)(g*160 + r))*FCK + c*8;
    lB[i] = (u16*)Bs + (w*40 + i*8) * 64;
  }

  float4v acc[4][5];
  #pragma unroll
  for (int mi = 0; mi < 4; ++mi)
    #pragma unroll
    for (int nj = 0; nj < 5; ++nj) acc[mi][nj] = (float4v){0.f,0.f,0.f,0.f};

  size_t kbase = (size_t)sp * 1152;
  for (int stp = 0; stp < 18; ++stp) {
    size_t kofs = kbase + (size_t)stp * 64;
    __syncthreads();
    #pragma unroll
    for (int i = 0; i < 4; ++i) load_lds16(gA[i] + kofs, lA[i]);
    #pragma unroll
    for (int i = 0; i < 5; ++i) load_lds16(gB[i] + kofs, lB[i]);
    __syncthreads();

    short8 a[4][2], bf[5][2];
    #pragma unroll
    for (int kb = 0; kb < 2; ++kb) {
      #pragma unroll
      for (int mi = 0; mi < 4; ++mi) {
        int row = wr*64 + mi*16 + l15;
        int cb  = (kb*64 + l4*16) ^ ((row & 7) << 4);
        a[mi][kb] = *(const short8*)((const char*)As + row*128 + cb);
      }
      #pragma unroll
      for (int nj = 0; nj < 5; ++nj) {
        int row = wc*80 + nj*16 + l15;
        int cb  = (kb*64 + l4*16) ^ ((row & 7) << 4);
        bf[nj][kb] = *(const short8*)((const char*)Bs + row*128 + cb);
      }
    }
    #pragma unroll
    for (int kb = 0; kb < 2; ++kb)
      #pragma unroll
      for (int mi = 0; mi < 4; ++mi)
        #pragma unroll
        for (int nj = 0; nj < 5; ++nj)
          acc[mi][nj] = __builtin_amdgcn_mfma_f32_16x16x32_bf16(
              a[mi][kb], bf[nj][kb], acc[mi][nj], 0, 0, 0);
  }

  #pragma unroll
  for (int mi = 0; mi < 4; ++mi)
    #pragma unroll
    for (int r = 0; r < 4; ++r) {
      int brow = wr*64 + mi*16 + l4*4 + r;
      #pragma unroll
      for (int nj = 0; nj < 5; ++nj) {
        int o = wc*80 + nj*16 + l15;
        atomicAdd(&accum[((size_t)brow*20 + g)*160 + o], acc[mi][nj][r]);
      }
    }
}

__global__ void k_final(const float* __restrict__ accum, const float* __restrict__ fcb,
                        float* __restrict__ out) {
  int idx = blockIdx.x * 256 + threadIdx.x;     // 128*3000
  if (idx >= B_*3000) return;
  unsigned b = (unsigned)idx / 3000u;
  unsigned rem = (unsigned)idx % 3000u;
  unsigned g = rem / 150u, o = rem % 150u;
  out[idx] = fmaxf(accum[((size_t)b*20 + g)*160 + o] + fcb[g*150 + o], 0.f);
}

extern "C" void kernel_launch(void* const* d_in, const int* in_sizes, int n_in,
                              void* d_out, int out_size, void* d_ws, size_t ws_size,
                              hipStream_t stream) {
  const float* x      = (const float*)d_in[0];
  const float* y      = (const float*)d_in[1];
  const float* conv_w = (const float*)d_in[2];
  const float* conv_b = (const float*)d_in[3];
  const float* fc_w   = (const float*)d_in[4];
  const float* fc_b   = (const float*)d_in[5];
  float* out = (float*)d_out;

  char* ws = (char*)d_ws;
  size_t off = 0;
  u16* Wb   = (u16*)(ws + off); off += (size_t)10240 * K2 * 2;        // 94.4 MB
  u16* up3  = (u16*)(ws + off); off += (size_t)G_ * B_ * 64 * C_ * 2; // 167.8 MB
  u16* feat = (u16*)(ws + off); off += (size_t)G_ * B_ * FCK * 2;     // 94.4 MB
  float* accum = (float*)(ws + off); off += (size_t)B_ * G_ * 160 * 4;// 1.6 MB
  int* cx = (int*)(ws + off); off += B_ * G_ * 4;
  int* cy = (int*)(ws + off); off += B_ * G_ * 4;
  u16* Wfcb = up3;   // alias: fc weights built AFTER conv consumed up3 (peak ws 358 MB)

  k_pos<<<1, 128, 0, stream>>>(y, cx, cy);
  k_convw<<<(10240*512)/256, 256, 0, stream>>>(conv_w, Wb);
  k_up3<<<B_*G_, 256, 0, stream>>>(x, cx, cy, up3);
  hipMemsetAsync(accum, 0, (size_t)B_ * G_ * 160 * 4, stream);
  k_conv<<<dim3(36, 4, 20), 256, 0, stream>>>(Wb, up3, conv_b, feat);
  k_fcw<<<(G_*160*2304)/256, 256, 0, stream>>>(fc_w, Wfcb);
  k_fc<<<dim3(16, 20), 256, 0, stream>>>(feat, Wfcb, accum);
  k_final<<<(B_*3000 + 255)/256, 256, 0, stream>>>(accum, fc_b, out);
}

// Round 2
// 873.238 us; speedup vs baseline: 1.5597x; 1.5597x over previous
//
#include <hip/hip_runtime.h>
#include <stdint.h>

#define B_  128
#define C_  512
#define G_  20
#define K2  4608      // C_*9, conv GEMM K
#define FCK 18432     // C_*36, fc GEMM K

typedef unsigned short u16;
typedef unsigned int   u32;
typedef __attribute__((ext_vector_type(8))) short  short8;
typedef __attribute__((ext_vector_type(4))) float  float4v;

__device__ __forceinline__ u16 f2bf(float f) {
  u32 u = __builtin_bit_cast(u32, f);
  u = (u + 0x7fffu + ((u >> 16) & 1u)) >> 16;   // RNE
  return (u16)u;
}

__device__ __forceinline__ void load_lds16(const void* g, void* l) {
  __builtin_amdgcn_global_load_lds(
      (const __attribute__((address_space(1))) void*)(uintptr_t)g,
      (__attribute__((address_space(3))) void*)(uint32_t)(uintptr_t)l,
      16, 0, 0);
}

// ---------------- landmarks -> integer crop positions ----------------
__global__ void k_pos(const float* __restrict__ y, int* __restrict__ cx, int* __restrict__ cy) {
  int b = blockIdx.x * blockDim.x + threadIdx.x;
  if (b >= B_) return;
  const int   I1[10] = {21,18,19,41,38,49,48,51,61,56};
  const int   I2[10] = {22,25,24,46,43,53,54,57,63,58};
  const float CF[10] = {-0.5f, -1.0f/3.0f, 1.0f/3.0f, 1.0f, 0.f,0.f,0.f,0.f,0.f, 0.5f};
  const float* yb = y + b * 136;
  float ruler = fabsf(yb[2*39] - yb[2*42]);
  for (int j = 0; j < 10; ++j) {
    float off = ruler * CF[j];
    float vx1 = yb[2*I1[j]];
    float vy1 = yb[2*I1[j]+1] + off;
    float vx2 = yb[2*I2[j]];
    float vy2 = yb[2*I2[j]+1] + off;
    int px1 = (int)(vx1 * 0.0625f); px1 = min(max(px1,1),12);
    int py1 = (int)(vy1 * 0.0625f); py1 = min(max(py1,1),12);
    int px2 = (int)(vx2 * 0.0625f); px2 = min(max(px2,1),12);
    int py2 = (int)(vy2 * 0.0625f); py2 = min(max(py2,1),12);
    cx[b*20 + 2*j]   = px1;  cx[b*20 + 2*j+1] = px2;
    cy[b*20 + 2*j]   = py1;  cy[b*20 + 2*j+1] = py2;
  }
}

// ------------- conv_w f32 [o][ci][t] -> bf16 Wb[o][t*512+ci] -------------
__global__ void k_convw(const float* __restrict__ w, u16* __restrict__ wb) {
  int tid = blockIdx.x * 256 + threadIdx.x;       // 10240*512 threads
  int o = tid >> 9, ci = tid & 511;
  const float* src = w + (size_t)tid * 9;         // (o*512+ci)*9
  u16* dst = wb + (size_t)o * K2 + ci;
  #pragma unroll
  for (int t = 0; t < 9; ++t) dst[t*512] = f2bf(src[t]);
}

// ------- fc_w f32 [g][i][o:150] -> bf16 Wfcb[g][o:160(pad0)][i] -------
// LDS-transposed: coalesced panel read, coalesced short8 writes.
__global__ void __launch_bounds__(256) k_fcw(const float* __restrict__ fw, u16* __restrict__ wfcb) {
  __shared__ u16 tile[128 * 161];                 // [il][o], stride 161 (conflict pad)
  int chunk = blockIdx.x;                         // 0..143 (FCK/128)
  int g     = blockIdx.y;
  int tid   = threadIdx.x;
  const float* src = fw + (size_t)g * FCK * 150 + (size_t)chunk * 128 * 150;
  #pragma unroll
  for (int it = 0; it < 75; ++it) {               // 75*256 = 19200 = 128*150
    int f = it * 256 + tid;
    int il = f / 150, o = f - il * 150;
    tile[il * 161 + o] = f2bf(src[f]);
  }
  __syncthreads();
  size_t dstbase = (size_t)g * 160 * FCK + (size_t)chunk * 128;
  #pragma unroll
  for (int it = 0; it < 10; ++it) {               // 10*256 = 2560 = 160*16
    int wi = it * 256 + tid;
    int o = wi >> 4, il8 = (wi & 15) * 8;
    u16 vals[8];
    if (o < 150) {
      #pragma unroll
      for (int j = 0; j < 8; ++j) vals[j] = tile[(il8 + j) * 161 + o];
    } else {
      #pragma unroll
      for (int j = 0; j < 8; ++j) vals[j] = 0;
    }
    *(short8*)(wfcb + dstbase + (size_t)o * FCK + il8) = *(short8*)vals;
  }
}

// ------- crop + bilinear 2x upsample -> up3[g][b][pp(8x8 pad)][ci] bf16 -------
__global__ void __launch_bounds__(256) k_up3(const float* __restrict__ x,
                                             const int* __restrict__ cx,
                                             const int* __restrict__ cy,
                                             u16* __restrict__ up3) {
  __shared__ float crop[3][3][C_];   // [r][s][ci]
  int bg = blockIdx.x;               // b*20+g
  int b = bg / 20, g = bg % 20;
  int X = cx[bg] - 1, Y = cy[bg] - 1;
  const float* xb = x + (size_t)b * (C_*14*14);
  int t = threadIdx.x;
  for (int it = 0; it < 6; ++it) {
    int idx = it*256 + t;            // 1536 = 512*3
    int r = idx >> 9, ci = idx & 511;
    const float* srow = xb + ci*196 + (Y + r)*14 + X;
    crop[r][0][ci] = srow[0];
    crop[r][1][ci] = srow[1];
    crop[r][2][ci] = srow[2];
  }
  __syncthreads();
  const int   R0[6] = {0,0,0,1,1,1};
  const float WA[6] = {1.f, .75f, .25f, .75f, .25f, 0.f};
  u16* dstbase = up3 + ((size_t)g*B_ + b) * 64 * C_;
  for (int it = 0; it < 16; ++it) {
    int cidx = it*256 + t;           // 4096 chunks of 8 ci
    int pp = cidx >> 6;
    int c8 = (cidx & 63) * 8;
    int ph = pp >> 3, pw = pp & 7;
    u16 outv[8];
    if (ph == 0 || ph == 7 || pw == 0 || pw == 7) {
      #pragma unroll
      for (int j = 0; j < 8; ++j) outv[j] = 0;
    } else {
      int oh = ph - 1, ow = pw - 1;
      int r0 = R0[oh]; float wy0 = WA[oh], wy1 = 1.f - WA[oh];
      int s0 = R0[ow]; float wx0 = WA[ow], wx1 = 1.f - WA[ow];
      #pragma unroll
      for (int j = 0; j < 8; ++j) {
        int ci = c8 + j;
        float v = wy0*(wx0*crop[r0][s0][ci]   + wx1*crop[r0][s0+1][ci])
                + wy1*(wx0*crop[r0+1][s0][ci] + wx1*crop[r0+1][s0+1][ci]);
        outv[j] = f2bf(v);
      }
    }
    *(short8*)(dstbase + (size_t)pp*C_ + c8) = *(short8*)outv;
  }
}

// ---------------- grouped conv as implicit GEMM (bf16 MFMA) ----------------
// per group g: D[co][n] = sum_k Wb[g*512+co][k] * P[n][k],  k=t*512+ci, n=b*36+pix
// Grid: 2880 1-D blocks, XCD-chunked swizzle (T1): each XCD gets 360 contiguous
// logical ids = exactly 10 (g,mt) A-panels; mt-reuse of B-tiles (stride 36) stays
// within the chunk -> A fetched ~1x, B ~1x instead of ~8x/~4x.
__global__ void __launch_bounds__(256) k_conv(const u16* __restrict__ wb,
                                              const u16* __restrict__ up3,
                                              const float* __restrict__ conv_b,
                                              u16* __restrict__ feat) {
  __shared__ __align__(16) u16 As[128*64];
  __shared__ __align__(16) u16 Bs[128*64];
  int bid = blockIdx.x;
  int lid = (bid & 7) * 360 + (bid >> 3);   // bijective: 2880 = 8*360
  int nt = lid % 36;                        // innermost: B-tile id
  int mt = (lid / 36) & 3;                  // A-panel row tile
  int g  = lid / 144;                       // group
  int tid = threadIdx.x;
  int lane = tid & 63, w = tid >> 6;
  int wr = w >> 1, wc = w & 1;
  int rl = lane >> 3, s = lane & 7;
  int l15 = lane & 15, l4 = lane >> 4;

  const u16* gA[4]; u16* lA[4];
  #pragma unroll
  for (int i = 0; i < 4; ++i) {
    int rA = w*32 + i*8 + rl;
    int c  = s ^ (rA & 7);                         // source pre-swizzle (rule #21)
    gA[i] = wb + (size_t)(g*512 + mt*128 + rA) * K2 + c*8;
    lA[i] = (u16*)As + (w*32 + i*8) * 64;
  }
  const u16* gB[4]; u16* lB[4];
  #pragma unroll
  for (int i = 0; i < 4; ++i) {
    int rB = w*32 + i*8 + rl;
    int n  = nt*128 + rB;
    unsigned bb = (unsigned)n / 36u;
    unsigned pix = (unsigned)n % 36u;
    int pixA = (int)(pix/6u)*8 + (int)(pix%6u);
    int c = s ^ (rB & 7);
    gB[i] = up3 + (((size_t)g*B_ + bb)*64 + pixA) * C_ + c*8;
    lB[i] = (u16*)Bs + (w*32 + i*8) * 64;
  }

  float4v acc[4][4];
  #pragma unroll
  for (int mi = 0; mi < 4; ++mi)
    #pragma unroll
    for (int nj = 0; nj < 4; ++nj) acc[mi][nj] = (float4v){0.f,0.f,0.f,0.f};

  for (int step = 0; step < 72; ++step) {
    int t9  = step >> 3;
    int ci0 = (step & 7) * 64;
    size_t kofsA = (size_t)step * 64;
    size_t kofsB = (size_t)((t9/3)*8 + (t9%3)) * C_ + ci0;  // pixel delta + ci
    __syncthreads();
    #pragma unroll
    for (int i = 0; i < 4; ++i) load_lds16(gA[i] + kofsA, lA[i]);
    #pragma unroll
    for (int i = 0; i < 4; ++i) load_lds16(gB[i] + kofsB, lB[i]);
    __syncthreads();   // compiler drains vmcnt before barrier (m97 structure)

    short8 a[4][2], bf[4][2];
    #pragma unroll
    for (int kb = 0; kb < 2; ++kb) {
      #pragma unroll
      for (int mi = 0; mi < 4; ++mi) {
        int row = wr*64 + mi*16 + l15;
        int cb  = (kb*64 + l4*16) ^ ((row & 7) << 4);
        a[mi][kb] = *(const short8*)((const char*)As + row*128 + cb);
      }
      #pragma unroll
      for (int nj = 0; nj < 4; ++nj) {
        int row = wc*64 + nj*16 + l15;
        int cb  = (kb*64 + l4*16) ^ ((row & 7) << 4);
        bf[nj][kb] = *(const short8*)((const char*)Bs + row*128 + cb);
      }
    }
    #pragma unroll
    for (int kb = 0; kb < 2; ++kb)
      #pragma unroll
      for (int mi = 0; mi < 4; ++mi)
        #pragma unroll
        for (int nj = 0; nj < 4; ++nj)
          acc[mi][nj] = __builtin_amdgcn_mfma_f32_16x16x32_bf16(
              a[mi][kb], bf[nj][kb], acc[mi][nj], 0, 0, 0);
  }

  // epilogue: bias + relu -> feat[g][b][co*36+pix] (bf16)
  float bias[4][4];
  #pragma unroll
  for (int mi = 0; mi < 4; ++mi)
    #pragma unroll
    for (int r = 0; r < 4; ++r)
      bias[mi][r] = conv_b[g*512 + mt*128 + wr*64 + mi*16 + l4*4 + r];
  #pragma unroll
  for (int nj = 0; nj < 4; ++nj) {
    int n = nt*128 + wc*64 + nj*16 + l15;
    unsigned bb = (unsigned)n / 36u;
    unsigned pix = (unsigned)n % 36u;
    size_t base = ((size_t)g*B_ + bb)*FCK + pix;
    #pragma unroll
    for (int mi = 0; mi < 4; ++mi)
      #pragma unroll
      for (int r = 0; r < 4; ++r) {
        int m = mt*128 + wr*64 + mi*16 + l4*4 + r;
        float v = fmaxf(acc[mi][nj][r] + bias[mi][r], 0.f);
        feat[base + (size_t)m*36] = f2bf(v);
      }
  }
}

// ---------------- FC: per-group [128 x 18432] x [18432 x 160], split-K ----------------
__global__ void __launch_bounds__(256) k_fc(const u16* __restrict__ feat,
                                            const u16* __restrict__ wfcb,
                                            float* __restrict__ accum) {
  __shared__ __align__(16) u16 As[128*64];
  __shared__ __align__(16) u16 Bs[160*64];
  int sp = blockIdx.x;   // 0..15 k-split
  int g  = blockIdx.y;
  int tid = threadIdx.x;
  int lane = tid & 63, w = tid >> 6;
  int wr = w >> 1, wc = w & 1;
  int rl = lane >> 3, s = lane & 7;
  int l15 = lane & 15, l4 = lane >> 4;

  const u16* gA[4]; u16* lA[4];
  #pragma unroll
  for (int i = 0; i < 4; ++i) {
    int r = w*32 + i*8 + rl;
    int c = s ^ (r & 7);
    gA[i] = feat + ((size_t)g*B_ + r)*FCK + c*8;
    lA[i] = (u16*)As + (w*32 + i*8) * 64;
  }
  const u16* gB[5]; u16* lB[5];
  #pragma unroll
  for (int i = 0; i < 5; ++i) {
    int r = w*40 + i*8 + rl;
    int c = s ^ (r & 7);
    gB[i] = wfcb + ((size_t)(g*160 + r))*FCK + c*8;
    lB[i] = (u16*)Bs + (w*40 + i*8) * 64;
  }

  float4v acc[4][5];
  #pragma unroll
  for (int mi = 0; mi < 4; ++mi)
    #pragma unroll
    for (int nj = 0; nj < 5; ++nj) acc[mi][nj] = (float4v){0.f,0.f,0.f,0.f};

  size_t kbase = (size_t)sp * 1152;
  for (int stp = 0; stp < 18; ++stp) {
    size_t kofs = kbase + (size_t)stp * 64;
    __syncthreads();
    #pragma unroll
    for (int i = 0; i < 4; ++i) load_lds16(gA[i] + kofs, lA[i]);
    #pragma unroll
    for (int i = 0; i < 5; ++i) load_lds16(gB[i] + kofs, lB[i]);
    __syncthreads();

    short8 a[4][2], bf[5][2];
    #pragma unroll
    for (int kb = 0; kb < 2; ++kb) {
      #pragma unroll
      for (int mi = 0; mi < 4; ++mi) {
        int row = wr*64 + mi*16 + l15;
        int cb  = (kb*64 + l4*16) ^ ((row & 7) << 4);
        a[mi][kb] = *(const short8*)((const char*)As + row*128 + cb);
      }
      #pragma unroll
      for (int nj = 0; nj < 5; ++nj) {
        int row = wc*80 + nj*16 + l15;
        int cb  = (kb*64 + l4*16) ^ ((row & 7) << 4);
        bf[nj][kb] = *(const short8*)((const char*)Bs + row*128 + cb);
      }
    }
    #pragma unroll
    for (int kb = 0; kb < 2; ++kb)
      #pragma unroll
      for (int mi = 0; mi < 4; ++mi)
        #pragma unroll
        for (int nj = 0; nj < 5; ++nj)
          acc[mi][nj] = __builtin_amdgcn_mfma_f32_16x16x32_bf16(
              a[mi][kb], bf[nj][kb], acc[mi][nj], 0, 0, 0);
  }

  #pragma unroll
  for (int mi = 0; mi < 4; ++mi)
    #pragma unroll
    for (int r = 0; r < 4; ++r) {
      int brow = wr*64 + mi*16 + l4*4 + r;
      #pragma unroll
      for (int nj = 0; nj < 5; ++nj) {
        int o = wc*80 + nj*16 + l15;
        atomicAdd(&accum[((size_t)brow*20 + g)*160 + o], acc[mi][nj][r]);
      }
    }
}

__global__ void k_final(const float* __restrict__ accum, const float* __restrict__ fcb,
                        float* __restrict__ out) {
  int idx = blockIdx.x * 256 + threadIdx.x;     // 128*3000
  if (idx >= B_*3000) return;
  unsigned b = (unsigned)idx / 3000u;
  unsigned rem = (unsigned)idx % 3000u;
  unsigned g = rem / 150u, o = rem % 150u;
  out[idx] = fmaxf(accum[((size_t)b*20 + g)*160 + o] + fcb[g*150 + o], 0.f);
}

extern "C" void kernel_launch(void* const* d_in, const int* in_sizes, int n_in,
                              void* d_out, int out_size, void* d_ws, size_t ws_size,
                              hipStream_t stream) {
  const float* x      = (const float*)d_in[0];
  const float* y      = (const float*)d_in[1];
  const float* conv_w = (const float*)d_in[2];
  const float* conv_b = (const float*)d_in[3];
  const float* fc_w   = (const float*)d_in[4];
  const float* fc_b   = (const float*)d_in[5];
  float* out = (float*)d_out;

  char* ws = (char*)d_ws;
  size_t off = 0;
  u16* Wb   = (u16*)(ws + off); off += (size_t)10240 * K2 * 2;        // 94.4 MB
  u16* up3  = (u16*)(ws + off); off += (size_t)G_ * B_ * 64 * C_ * 2; // 167.8 MB
  u16* feat = (u16*)(ws + off); off += (size_t)G_ * B_ * FCK * 2;     // 94.4 MB
  float* accum = (float*)(ws + off); off += (size_t)B_ * G_ * 160 * 4;// 1.6 MB
  int* cx = (int*)(ws + off); off += B_ * G_ * 4;
  int* cy = (int*)(ws + off); off += B_ * G_ * 4;
  u16* Wfcb = up3;   // alias: fc weights built AFTER conv consumed up3 (peak ws 358 MB)

  k_pos<<<1, 128, 0, stream>>>(y, cx, cy);
  k_convw<<<(10240*512)/256, 256, 0, stream>>>(conv_w, Wb);
  k_up3<<<B_*G_, 256, 0, stream>>>(x, cx, cy, up3);
  hipMemsetAsync(accum, 0, (size_t)B_ * G_ * 160 * 4, stream);
  k_conv<<<2880, 256, 0, stream>>>(Wb, up3, conv_b, feat);
  k_fcw<<<dim3(144, 20), 256, 0, stream>>>(fc_w, Wfcb);
  k_fc<<<dim3(16, 20), 256, 0, stream>>>(feat, Wfcb, accum);
  k_final<<<(B_*3000 + 255)/256, 256, 0, stream>>>(accum, fc_b, out);
}

// Round 3
// 676.555 us; speedup vs baseline: 2.0132x; 1.2907x over previous
//
#include <hip/hip_runtime.h>
#include <stdint.h>

#define B_  128
#define C_  512
#define G_  20
#define K2  4608      // C_*9, conv GEMM K
#define FCK 18432     // C_*36, fc GEMM K

typedef unsigned short u16;
typedef unsigned int   u32;
typedef __attribute__((ext_vector_type(8))) short  short8;
typedef __attribute__((ext_vector_type(4))) float  float4v;

__device__ __forceinline__ u16 f2bf(float f) {
  u32 u = __builtin_bit_cast(u32, f);
  u = (u + 0x7fffu + ((u >> 16) & 1u)) >> 16;   // RNE
  return (u16)u;
}

__device__ __forceinline__ void load_lds16(const void* g, void* l) {
  __builtin_amdgcn_global_load_lds(
      (const __attribute__((address_space(1))) void*)(uintptr_t)g,
      (__attribute__((address_space(3))) void*)(uint32_t)(uintptr_t)l,
      16, 0, 0);
}

// ---------------- landmarks -> integer crop positions ----------------
__global__ void k_pos(const float* __restrict__ y, int* __restrict__ cx, int* __restrict__ cy) {
  int b = blockIdx.x * blockDim.x + threadIdx.x;
  if (b >= B_) return;
  const int   I1[10] = {21,18,19,41,38,49,48,51,61,56};
  const int   I2[10] = {22,25,24,46,43,53,54,57,63,58};
  const float CF[10] = {-0.5f, -1.0f/3.0f, 1.0f/3.0f, 1.0f, 0.f,0.f,0.f,0.f,0.f, 0.5f};
  const float* yb = y + b * 136;
  float ruler = fabsf(yb[2*39] - yb[2*42]);
  for (int j = 0; j < 10; ++j) {
    float off = ruler * CF[j];
    float vx1 = yb[2*I1[j]];
    float vy1 = yb[2*I1[j]+1] + off;
    float vx2 = yb[2*I2[j]];
    float vy2 = yb[2*I2[j]+1] + off;
    int px1 = (int)(vx1 * 0.0625f); px1 = min(max(px1,1),12);
    int py1 = (int)(vy1 * 0.0625f); py1 = min(max(py1,1),12);
    int px2 = (int)(vx2 * 0.0625f); px2 = min(max(px2,1),12);
    int py2 = (int)(vy2 * 0.0625f); py2 = min(max(py2,1),12);
    cx[b*20 + 2*j]   = px1;  cx[b*20 + 2*j+1] = px2;
    cy[b*20 + 2*j]   = py1;  cy[b*20 + 2*j+1] = py2;
  }
}

// ------------- conv_w f32 [o][ci][t] -> bf16 Wb[o][t*512+ci] -------------
__global__ void k_convw(const float* __restrict__ w, u16* __restrict__ wb) {
  int tid = blockIdx.x * 256 + threadIdx.x;       // 10240*512 threads
  int o = tid >> 9, ci = tid & 511;
  const float* src = w + (size_t)tid * 9;         // (o*512+ci)*9
  u16* dst = wb + (size_t)o * K2 + ci;
  #pragma unroll
  for (int t = 0; t < 9; ++t) dst[t*512] = f2bf(src[t]);
}

// ------- fc_w f32 [g][i][o:150] -> bf16 Wfcb[g][o:160(pad0)][i] -------
// LDS-transposed: coalesced panel read, coalesced short8 writes.
__global__ void __launch_bounds__(256) k_fcw(const float* __restrict__ fw, u16* __restrict__ wfcb) {
  __shared__ u16 tile[128 * 161];                 // [il][o], stride 161 (conflict pad)
  int chunk = blockIdx.x;                         // 0..143 (FCK/128)
  int g     = blockIdx.y;
  int tid   = threadIdx.x;
  const float* src = fw + (size_t)g * FCK * 150 + (size_t)chunk * 128 * 150;
  #pragma unroll
  for (int it = 0; it < 75; ++it) {               // 75*256 = 19200 = 128*150
    int f = it * 256 + tid;
    int il = f / 150, o = f - il * 150;
    tile[il * 161 + o] = f2bf(src[f]);
  }
  __syncthreads();
  size_t dstbase = (size_t)g * 160 * FCK + (size_t)chunk * 128;
  #pragma unroll
  for (int it = 0; it < 10; ++it) {               // 10*256 = 2560 = 160*16
    int wi = it * 256 + tid;
    int o = wi >> 4, il8 = (wi & 15) * 8;
    u16 vals[8];
    if (o < 150) {
      #pragma unroll
      for (int j = 0; j < 8; ++j) vals[j] = tile[(il8 + j) * 161 + o];
    } else {
      #pragma unroll
      for (int j = 0; j < 8; ++j) vals[j] = 0;
    }
    *(short8*)(wfcb + dstbase + (size_t)o * FCK + il8) = *(short8*)vals;
  }
}

// ------- crop + bilinear 2x upsample -> up3[g][b][pp(8x8 pad)][ci] bf16 -------
__global__ void __launch_bounds__(256) k_up3(const float* __restrict__ x,
                                             const int* __restrict__ cx,
                                             const int* __restrict__ cy,
                                             u16* __restrict__ up3) {
  __shared__ float crop[3][3][C_];   // [r][s][ci]
  int bg = blockIdx.x;               // b*20+g
  int b = bg / 20, g = bg % 20;
  int X = cx[bg] - 1, Y = cy[bg] - 1;
  const float* xb = x + (size_t)b * (C_*14*14);
  int t = threadIdx.x;
  for (int it = 0; it < 6; ++it) {
    int idx = it*256 + t;            // 1536 = 512*3
    int r = idx >> 9, ci = idx & 511;
    const float* srow = xb + ci*196 + (Y + r)*14 + X;
    crop[r][0][ci] = srow[0];
    crop[r][1][ci] = srow[1];
    crop[r][2][ci] = srow[2];
  }
  __syncthreads();
  const int   R0[6] = {0,0,0,1,1,1};
  const float WA[6] = {1.f, .75f, .25f, .75f, .25f, 0.f};
  u16* dstbase = up3 + ((size_t)g*B_ + b) * 64 * C_;
  for (int it = 0; it < 16; ++it) {
    int cidx = it*256 + t;           // 4096 chunks of 8 ci
    int pp = cidx >> 6;
    int c8 = (cidx & 63) * 8;
    int ph = pp >> 3, pw = pp & 7;
    u16 outv[8];
    if (ph == 0 || ph == 7 || pw == 0 || pw == 7) {
      #pragma unroll
      for (int j = 0; j < 8; ++j) outv[j] = 0;
    } else {
      int oh = ph - 1, ow = pw - 1;
      int r0 = R0[oh]; float wy0 = WA[oh], wy1 = 1.f - WA[oh];
      int s0 = R0[ow]; float wx0 = WA[ow], wx1 = 1.f - WA[ow];
      #pragma unroll
      for (int j = 0; j < 8; ++j) {
        int ci = c8 + j;
        float v = wy0*(wx0*crop[r0][s0][ci]   + wx1*crop[r0][s0+1][ci])
                + wy1*(wx0*crop[r0+1][s0][ci] + wx1*crop[r0+1][s0+1][ci]);
        outv[j] = f2bf(v);
      }
    }
    *(short8*)(dstbase + (size_t)pp*C_ + c8) = *(short8*)outv;
  }
}

// ---------------- grouped conv as implicit GEMM (bf16 MFMA) ----------------
// per group g: D[co][n] = sum_k Wb[g*512+co][k] * P[n][k],  k=t*512+ci, n=b*36+pix
// BM=256 (2 co-subtiles fused), BN=128, BK=64, 512 threads / 8 waves (4M x 2N),
// each wave 64x64 out. Grid 1440 = 20g x 36nt x 2mt, XCD-chunked with mt
// INNERMOST so the 2 blocks sharing a B-tile are adjacent lids (same XCD,
// back-to-back) -> B fetched ~1x, A slices L2-shared across lockstep nt blocks.
__global__ void __launch_bounds__(512) k_conv(const u16* __restrict__ wb,
                                              const u16* __restrict__ up3,
                                              const float* __restrict__ conv_b,
                                              u16* __restrict__ feat) {
  __shared__ __align__(16) u16 As[256*64];
  __shared__ __align__(16) u16 Bs[128*64];
  int bid = blockIdx.x;
  int lid = (bid & 7) * 180 + (bid >> 3);   // bijective: 1440 = 8*180
  int mt = lid & 1;                          // innermost: A-subtile (B-reuse pair)
  int nt = (lid >> 1) % 36;                  // B-tile id
  int g  = lid / 72;                         // group
  int tid = threadIdx.x;
  int lane = tid & 63, w = tid >> 6;         // 8 waves
  int wr = w >> 1, wc = w & 1;               // wave grid 4M x 2N
  int rl = lane >> 3, s = lane & 7;
  int l15 = lane & 15, l4 = lane >> 4;

  const u16* gA[4]; u16* lA[4];
  #pragma unroll
  for (int i = 0; i < 4; ++i) {
    int rA = w*32 + i*8 + rl;                // 0..255
    int c  = s ^ (rA & 7);                   // source pre-swizzle (rule #21)
    gA[i] = wb + (size_t)(g*512 + mt*256 + rA) * K2 + c*8;
    lA[i] = (u16*)As + (w*32 + i*8) * 64;
  }
  const u16* gB[2]; u16* lB[2];
  #pragma unroll
  for (int i = 0; i < 2; ++i) {
    int rB = w*16 + i*8 + rl;                // 0..127
    int n  = nt*128 + rB;
    unsigned bb = (unsigned)n / 36u;
    unsigned pix = (unsigned)n % 36u;
    int pixA = (int)(pix/6u)*8 + (int)(pix%6u);
    int c = s ^ (rB & 7);
    gB[i] = up3 + (((size_t)g*B_ + bb)*64 + pixA) * C_ + c*8;
    lB[i] = (u16*)Bs + (w*16 + i*8) * 64;
  }

  float4v acc[4][4];
  #pragma unroll
  for (int mi = 0; mi < 4; ++mi)
    #pragma unroll
    for (int nj = 0; nj < 4; ++nj) acc[mi][nj] = (float4v){0.f,0.f,0.f,0.f};

  for (int step = 0; step < 72; ++step) {
    int t9  = step >> 3;
    int ci0 = (step & 7) * 64;
    size_t kofsA = (size_t)step * 64;
    size_t kofsB = (size_t)((t9/3)*8 + (t9%3)) * C_ + ci0;  // pixel delta + ci
    __syncthreads();
    #pragma unroll
    for (int i = 0; i < 4; ++i) load_lds16(gA[i] + kofsA, lA[i]);
    #pragma unroll
    for (int i = 0; i < 2; ++i) load_lds16(gB[i] + kofsB, lB[i]);
    __syncthreads();   // compiler drains vmcnt before barrier (m97 structure)

    short8 a[4][2], bf[4][2];
    #pragma unroll
    for (int kb = 0; kb < 2; ++kb) {
      #pragma unroll
      for (int mi = 0; mi < 4; ++mi) {
        int row = wr*64 + mi*16 + l15;       // 0..255
        int cb  = (kb*64 + l4*16) ^ ((row & 7) << 4);
        a[mi][kb] = *(const short8*)((const char*)As + row*128 + cb);
      }
      #pragma unroll
      for (int nj = 0; nj < 4; ++nj) {
        int row = wc*64 + nj*16 + l15;       // 0..127
        int cb  = (kb*64 + l4*16) ^ ((row & 7) << 4);
        bf[nj][kb] = *(const short8*)((const char*)Bs + row*128 + cb);
      }
    }
    #pragma unroll
    for (int kb = 0; kb < 2; ++kb)
      #pragma unroll
      for (int mi = 0; mi < 4; ++mi)
        #pragma unroll
        for (int nj = 0; nj < 4; ++nj)
          acc[mi][nj] = __builtin_amdgcn_mfma_f32_16x16x32_bf16(
              a[mi][kb], bf[nj][kb], acc[mi][nj], 0, 0, 0);
  }

  // epilogue: bias + relu -> feat[g][b][co*36+pix] (bf16)
  float bias[4][4];
  #pragma unroll
  for (int mi = 0; mi < 4; ++mi)
    #pragma unroll
    for (int r = 0; r < 4; ++r)
      bias[mi][r] = conv_b[g*512 + mt*256 + wr*64 + mi*16 + l4*4 + r];
  #pragma unroll
  for (int nj = 0; nj < 4; ++nj) {
    int n = nt*128 + wc*64 + nj*16 + l15;
    unsigned bb = (unsigned)n / 36u;
    unsigned pix = (unsigned)n % 36u;
    size_t base = ((size_t)g*B_ + bb)*FCK + pix;
    #pragma unroll
    for (int mi = 0; mi < 4; ++mi)
      #pragma unroll
      for (int r = 0; r < 4; ++r) {
        int m = mt*256 + wr*64 + mi*16 + l4*4 + r;
        float v = fmaxf(acc[mi][nj][r] + bias[mi][r], 0.f);
        feat[base + (size_t)m*36] = f2bf(v);
      }
  }
}

// ---------------- FC: per-group [128 x 18432] x [18432 x 160], split-K ----------------
__global__ void __launch_bounds__(256) k_fc(const u16* __restrict__ feat,
                                            const u16* __restrict__ wfcb,
                                            float* __restrict__ accum) {
  __shared__ __align__(16) u16 As[128*64];
  __shared__ __align__(16) u16 Bs[160*64];
  int sp = blockIdx.x;   // 0..15 k-split
  int g  = blockIdx.y;
  int tid = threadIdx.x;
  int lane = tid & 63, w = tid >> 6;
  int wr = w >> 1, wc = w & 1;
  int rl = lane >> 3, s = lane & 7;
  int l15 = lane & 15, l4 = lane >> 4;

  const u16* gA[4]; u16* lA[4];
  #pragma unroll
  for (int i = 0; i < 4; ++i) {
    int r = w*32 + i*8 + rl;
    int c = s ^ (r & 7);
    gA[i] = feat + ((size_t)g*B_ + r)*FCK + c*8;
    lA[i] = (u16*)As + (w*32 + i*8) * 64;
  }
  const u16* gB[5]; u16* lB[5];
  #pragma unroll
  for (int i = 0; i < 5; ++i) {
    int r = w*40 + i*8 + rl;
    int c = s ^ (r & 7);
    gB[i] = wfcb + ((size_t)(g*160 + r))*FCK + c*8;
    lB[i] = (u16*)Bs + (w*40 + i*8) * 64;
  }

  float4v acc[4][5];
  #pragma unroll
  for (int mi = 0; mi < 4; ++mi)
    #pragma unroll
    for (int nj = 0; nj < 5; ++nj) acc[mi][nj] = (float4v){0.f,0.f,0.f,0.f};

  size_t kbase = (size_t)sp * 1152;
  for (int stp = 0; stp < 18; ++stp) {
    size_t kofs = kbase + (size_t)stp * 64;
    __syncthreads();
    #pragma unroll
    for (int i = 0; i < 4; ++i) load_lds16(gA[i] + kofs, lA[i]);
    #pragma unroll
    for (int i = 0; i < 5; ++i) load_lds16(gB[i] + kofs, lB[i]);
    __syncthreads();

    short8 a[4][2], bf[5][2];
    #pragma unroll
    for (int kb = 0; kb < 2; ++kb) {
      #pragma unroll
      for (int mi = 0; mi < 4; ++mi) {
        int row = wr*64 + mi*16 + l15;
        int cb  = (kb*64 + l4*16) ^ ((row & 7) << 4);
        a[mi][kb] = *(const short8*)((const char*)As + row*128 + cb);
      }
      #pragma unroll
      for (int nj = 0; nj < 5; ++nj) {
        int row = wc*80 + nj*16 + l15;
        int cb  = (kb*64 + l4*16) ^ ((row & 7) << 4);
        bf[nj][kb] = *(const short8*)((const char*)Bs + row*128 + cb);
      }
    }
    #pragma unroll
    for (int kb = 0; kb < 2; ++kb)
      #pragma unroll
      for (int mi = 0; mi < 4; ++mi)
        #pragma unroll
        for (int nj = 0; nj < 5; ++nj)
          acc[mi][nj] = __builtin_amdgcn_mfma_f32_16x16x32_bf16(
              a[mi][kb], bf[nj][kb], acc[mi][nj], 0, 0, 0);
  }

  #pragma unroll
  for (int mi = 0; mi < 4; ++mi)
    #pragma unroll
    for (int r = 0; r < 4; ++r) {
      int brow = wr*64 + mi*16 + l4*4 + r;
      #pragma unroll
      for (int nj = 0; nj < 5; ++nj) {
        int o = wc*80 + nj*16 + l15;
        atomicAdd(&accum[((size_t)brow*20 + g)*160 + o], acc[mi][nj][r]);
      }
    }
}

__global__ void k_final(const float* __restrict__ accum, const float* __restrict__ fcb,
                        float* __restrict__ out) {
  int idx = blockIdx.x * 256 + threadIdx.x;     // 128*3000
  if (idx >= B_*3000) return;
  unsigned b = (unsigned)idx / 3000u;
  unsigned rem = (unsigned)idx % 3000u;
  unsigned g = rem / 150u, o = rem % 150u;
  out[idx] = fmaxf(accum[((size_t)b*20 + g)*160 + o] + fcb[g*150 + o], 0.f);
}

extern "C" void kernel_launch(void* const* d_in, const int* in_sizes, int n_in,
                              void* d_out, int out_size, void* d_ws, size_t ws_size,
                              hipStream_t stream) {
  const float* x      = (const float*)d_in[0];
  const float* y      = (const float*)d_in[1];
  const float* conv_w = (const float*)d_in[2];
  const float* conv_b = (const float*)d_in[3];
  const float* fc_w   = (const float*)d_in[4];
  const float* fc_b   = (const float*)d_in[5];
  float* out = (float*)d_out;

  char* ws = (char*)d_ws;
  size_t off = 0;
  u16* Wb   = (u16*)(ws + off); off += (size_t)10240 * K2 * 2;        // 94.4 MB
  u16* up3  = (u16*)(ws + off); off += (size_t)G_ * B_ * 64 * C_ * 2; // 167.8 MB
  u16* feat = (u16*)(ws + off); off += (size_t)G_ * B_ * FCK * 2;     // 94.4 MB
  float* accum = (float*)(ws + off); off += (size_t)B_ * G_ * 160 * 4;// 1.6 MB
  int* cx = (int*)(ws + off); off += B_ * G_ * 4;
  int* cy = (int*)(ws + off); off += B_ * G_ * 4;
  u16* Wfcb = up3;   // alias: fc weights built AFTER conv consumed up3 (peak ws 358 MB)

  k_pos<<<1, 128, 0, stream>>>(y, cx, cy);
  k_convw<<<(10240*512)/256, 256, 0, stream>>>(conv_w, Wb);
  k_up3<<<B_*G_, 256, 0, stream>>>(x, cx, cy, up3);
  hipMemsetAsync(accum, 0, (size_t)B_ * G_ * 160 * 4, stream);
  k_conv<<<1440, 512, 0, stream>>>(Wb, up3, conv_b, feat);
  k_fcw<<<dim3(144, 20), 256, 0, stream>>>(fc_w, Wfcb);
  k_fc<<<dim3(16, 20), 256, 0, stream>>>(feat, Wfcb, accum);
  k_final<<<(B_*3000 + 255)/256, 256, 0, stream>>>(accum, fc_b, out);
}